// Round 6
// baseline (231.084 us; speedup 1.0000x reference)
//
#include <hip/hip_runtime.h>
#include <hip/hip_bf16.h>
#include <cstdint>

#define NN    50000
#define NE    1600000
#define DIN   256
#define DOUT  64

#define BKT   196     // coarse buckets: src>>8 (256 nodes each), 49999>>8 = 195
#define BCAP  10240   // edges per coarse bucket capacity (mean 8163, +22 sigma)
#define EPB   8192    // edges per binning block
#define EPT   32      // EPB / 256
#define NBIN  196     // ceil(NE / EPB)
#define MTB   64      // rows per gemm block
#define NGEMM 782     // ceil(NN / MTB)
#define SCAP  1536    // agg stage: edges per 32-node slice (mean 1024, +16 sigma)

typedef __attribute__((ext_vector_type(8))) short frag8;   // 8 bf16 (4 VGPRs)
typedef __attribute__((ext_vector_type(4))) float fragc;   // 4 fp32 acc

union PK { __hip_bfloat162 b2; uint32_t u; };
union CH { frag8 v; uint32_t u[4]; };

__device__ __forceinline__ float leaky01(float x) { return x >= 0.f ? x : 0.01f * x; }

__device__ __forceinline__ uint32_t pk2(float lo, float hi) {
  PK p; p.b2 = __float22bfloat162_rn(make_float2(lo, hi)); return p.u;  // (hi<<16)|lo
}

__device__ __forceinline__ int   bcast_i(int v, int lane) {
  return __builtin_amdgcn_readlane(v, lane);
}
__device__ __forceinline__ float bcast_f(float v, int lane) {
  return __int_as_float(__builtin_amdgcn_readlane(__float_as_int(v), lane));
}

// bf16 pair unpack: u = (Lbits<<16) | Hbits
__device__ __forceinline__ float bfH(uint32_t u) { return __uint_as_float(u << 16); }
__device__ __forceinline__ float bfL(uint32_t u) { return __uint_as_float(u & 0xffff0000u); }

// -------------------------------------------------------------------------
// prep: zero bucket cursors + build Wt = bf16 transposed weights [m][n][k]
// -------------------------------------------------------------------------
__global__ __launch_bounds__(256) void prep_kernel(
    const float* __restrict__ Wh, const float* __restrict__ Wl,
    __hip_bfloat16* __restrict__ Wt, int* __restrict__ cursor)
{
  if (blockIdx.x == 0 && threadIdx.x < BKT) cursor[threadIdx.x] = 0;
  int g = blockIdx.x * 256 + threadIdx.x;
  if (g < 2 * DOUT * DIN) {
    int m = g >> 14, rem = g & 16383;
    int n = rem >> 8, k = rem & 255;
    float v = (m ? Wl : Wh)[k * DOUT + n];
    Wt[g] = __float2bfloat16(v);
  }
}

// -------------------------------------------------------------------------
// Fused kernel:
//  blocks [0, NBIN): binning role — LDS counting-sort of 8192 edges into 196
//    coarse buckets (src>>8). Per-wave hist/cur copies (4x fewer LDS-atomic
//    serializations), parallel Hillis-Steele scan, NO binary search on
//    writeout (bucket id read from the staged word).
//  blocks [NBIN, NBIN+NGEMM): MFMA gemm role — 64 rows/block, bf16 16x16x32.
// -------------------------------------------------------------------------
__global__ __launch_bounds__(256) void fused_kernel(
    const float* __restrict__ inp, const __hip_bfloat16* __restrict__ Wt,
    const float* __restrict__ ah, const float* __restrict__ al,
    const int* __restrict__ edge, int* __restrict__ cursor,
    uint32_t* __restrict__ binned, uint32_t* __restrict__ HL,
    float2* __restrict__ ss)
{
  __shared__ __align__(16) char smem[45056];   // overlay: binning / A frags

  const int idx = blockIdx.x;
  const int t = threadIdx.x;

  if (idx < NBIN) {
    // ---------------- binning role ----------------
    uint32_t* stage = (uint32_t*)smem;              // 32768 B
    int* hist4 = (int*)(smem + 32768);              // 4096 B (-> wavebase)
    int* cur4  = (int*)(smem + 36864);              // 4096 B
    int* histT = (int*)(smem + 40960);              // 1024 B
    int* scn   = (int*)(smem + 41984);              // 1024 B
    int* sexc  = (int*)(smem + 43008);              // 1024 B
    int* bg    = (int*)(smem + 44032);              // 1024 B

    const int w = t >> 6;                           // wave id 0..3
    const int e0 = idx * EPB;
    uint32_t v[EPT];
#pragma unroll
    for (int i = 0; i < EPT; i++) {
      int e = e0 + i * 256 + t;
      if (e < NE) {
        v[i] = ((uint32_t)edge[e] << 16) | (uint32_t)edge[NE + e];
      } else {
        v[i] = 0xFFFFFFFFu;              // bin 255 -> skipped
      }
    }
    hist4[t] = 0; hist4[256 + t] = 0; hist4[512 + t] = 0; hist4[768 + t] = 0;
    cur4[t]  = 0; cur4[256 + t]  = 0; cur4[512 + t]  = 0; cur4[768 + t]  = 0;
    __syncthreads();
#pragma unroll
    for (int i = 0; i < EPT; i++) {
      int b = v[i] >> 24;
      if (b < BKT) atomicAdd(&hist4[(w << 8) + b], 1);
    }
    __syncthreads();
    {
      int h0 = hist4[t], h1 = hist4[256 + t], h2 = hist4[512 + t], h3 = hist4[768 + t];
      hist4[t] = 0; hist4[256 + t] = h0; hist4[512 + t] = h0 + h1; hist4[768 + t] = h0 + h1 + h2;
      int hb = h0 + h1 + h2 + h3;
      histT[t] = hb;
      scn[t] = hb;
    }
    __syncthreads();
    for (int off = 1; off < 256; off <<= 1) {       // inclusive scan, 8 rounds
      int vv = scn[t] + ((t >= off) ? scn[t - off] : 0);
      __syncthreads();
      scn[t] = vv;
      __syncthreads();
    }
    {
      sexc[t] = scn[t] - histT[t];                  // exclusive prefix
      bg[t] = histT[t] ? atomicAdd(&cursor[t], histT[t]) : 0;
    }
    __syncthreads();
#pragma unroll
    for (int i = 0; i < EPT; i++) {
      int b = v[i] >> 24;
      if (b < BKT) {
        int pos = atomicAdd(&cur4[(w << 8) + b], 1);
        stage[sexc[b] + hist4[(w << 8) + b] + pos] = v[i];
      }
    }
    __syncthreads();
    const int total = scn[255];
    for (int i = t; i < total; i += 256) {
      uint32_t vv = stage[i];
      int lo = vv >> 24;                            // bucket id from the word
      int ofs = bg[lo] + (i - sexc[lo]);
      if (ofs < BCAP) binned[(size_t)lo * BCAP + ofs] = vv;
    }
    return;
  }

  // ---------------- MFMA gemm role ----------------
  frag8* asmem = (frag8*)smem;             // 2048 chunks x 16B
  const int gid = idx - NBIN;              // 0 .. NGEMM-1
  const int n0 = gid * MTB;
  const int lane = t & 63;
  const int w = t >> 6;                    // wave id: rows w*16..w*16+15
  const int quad = lane >> 4, nn = lane & 15;

  const float4* inp4 = (const float4*)inp;
#pragma unroll
  for (int i = 0; i < 8; i++) {
    int c = i * 256 + t;
    int r = c & 15;
    int cc = c >> 4;
    int qd = cc & 3;
    int wq = cc >> 2;                      // w*8 + q
    int row = ((wq >> 3) << 4) + r;
    int k0 = ((wq & 7) << 5) + (qd << 3);
    int node = n0 + row;
    float4 a0 = make_float4(0.f, 0.f, 0.f, 0.f), a1 = a0;
    if (node < NN) {
      a0 = inp4[(size_t)node * 64 + (k0 >> 2)];
      a1 = inp4[(size_t)node * 64 + (k0 >> 2) + 1];
    }
    CH ch;
    ch.u[0] = pk2(a0.x, a0.y);
    ch.u[1] = pk2(a0.z, a0.w);
    ch.u[2] = pk2(a1.x, a1.y);
    ch.u[3] = pk2(a1.z, a1.w);
    asmem[c] = ch.v;
  }
  __syncthreads();

  fragc accH[4], accL[4];
#pragma unroll
  for (int c = 0; c < 4; c++) {
    accH[c] = (fragc){0.f, 0.f, 0.f, 0.f};
    accL[c] = (fragc){0.f, 0.f, 0.f, 0.f};
  }

  const frag8* Wt8 = (const frag8*)Wt;     // [m*64 + n'][32 k-chunks]
#pragma unroll
  for (int q = 0; q < 8; q++) {
    frag8 af = asmem[(w << 9) + (q << 6) + lane];   // A[m=nn][k=q*32+quad*8+j]
#pragma unroll
    for (int c = 0; c < 4; c++) {
      frag8 bh = Wt8[(c * 16 + nn) * 32 + q * 4 + quad];        // B[k][n=c*16+nn]
      frag8 bl = Wt8[(64 + c * 16 + nn) * 32 + q * 4 + quad];
      accH[c] = __builtin_amdgcn_mfma_f32_16x16x32_bf16(af, bh, accH[c], 0, 0, 0);
      accL[c] = __builtin_amdgcn_mfma_f32_16x16x32_bf16(af, bl, accL[c], 0, 0, 0);
    }
  }

  // Epilogue: C/D mapping col=lane&15 (n), row=quad*4+reg (m89-verified).
  float ahv[4], alv[4];
#pragma unroll
  for (int c = 0; c < 4; c++) { ahv[c] = ah[c * 16 + nn]; alv[c] = al[c * 16 + nn]; }
#pragma unroll
  for (int r = 0; r < 4; r++) {
    int node = n0 + (w << 4) + (quad << 2) + r;
    float sH = 0.f, sL = 0.f;
#pragma unroll
    for (int c = 0; c < 4; c++) {
      float hH = leaky01(accH[c][r]);
      float hL = leaky01(accL[c][r]);
      if (node < NN) HL[(size_t)node * DOUT + c * 16 + nn] = pk2(hH, hL);
      sH += hH * ahv[c];
      sL += hL * alv[c];
    }
#pragma unroll
    for (int off = 1; off < 16; off <<= 1) {   // reduce over n within quad
      sH += __shfl_xor(sH, off);
      sL += __shfl_xor(sL, off);
    }
    if (nn == 0 && node < NN) ss[node] = make_float2(sH, sL);
  }
}

// -------------------------------------------------------------------------
// agg: one block per (bucket, 32-node slice). Re-reads the bucket's binned
// edges (L2-hot), counting-sorts its slice's edges into a 6KB LDS stage
// (replaces the csr kernel + col round-trip), then gathers:
// lane d owns feature dim d; j-loop unrolled x8 for 8 outstanding gathers.
// -------------------------------------------------------------------------
__global__ __launch_bounds__(256) void agg_kernel(
    const uint32_t* __restrict__ binned, const int* __restrict__ cursor,
    const uint32_t* __restrict__ HL, const float2* __restrict__ ss,
    float* __restrict__ out)
{
  __shared__ uint32_t stg[SCAP];
  __shared__ int cnt[32], cur[32], scn[32], stt[32];
  const int b = blockIdx.x >> 3, sub = blockIdx.x & 7;
  const int t = threadIdx.x;
  if (t < 32) { cnt[t] = 0; cur[t] = 0; }
  __syncthreads();
  int nE = cursor[b]; if (nE > BCAP) nE = BCAP;
  const uint32_t* eb = binned + (size_t)b * BCAP;

  for (int i = t; i < nE; i += 256) {
    uint32_t v = eb[i];
    int loc = (v >> 16) & 255;
    if ((loc >> 5) == sub) atomicAdd(&cnt[loc & 31], 1);
  }
  __syncthreads();
  if (t < 32) scn[t] = cnt[t];
  __syncthreads();
  for (int off = 1; off < 32; off <<= 1) {
    int vv = 0;
    if (t < 32) vv = scn[t] + ((t >= off) ? scn[t - off] : 0);
    __syncthreads();
    if (t < 32) scn[t] = vv;
    __syncthreads();
  }
  if (t < 32) stt[t] = scn[t] - cnt[t];
  __syncthreads();
  for (int i = t; i < nE; i += 256) {
    uint32_t v = eb[i];
    int loc = (v >> 16) & 255;
    if ((loc >> 5) == sub) {
      int l = loc & 31;
      int pos = atomicAdd(&cur[l], 1);
      int o = stt[l] + pos;
      if (o < SCAP) stg[o] = v;
    }
  }
  __syncthreads();

  const int w = t >> 6, lane = t & 63;
  for (int i = 0; i < 8; i++) {
    int l = (w << 3) + i;
    int node = (b << 8) + (sub << 5) + l;
    if (node >= NN) continue;
    int d = cnt[l];
    int st = stt[l];
    if (st + d > SCAP) d = SCAP - st;    // clamp (never in practice)
    if (d < 0) d = 0;
    float2 sn = ss[node];

    float accH = 0.f, accL = 0.f, rsH = 0.f, rsL = 0.f;
    for (int base = 0; base < d; base += 64) {
      int m = d - base; if (m > 64) m = 64;
      int   dst_l = 0;
      float eh_l = 0.f, el_l = 0.f;
      if (lane < m) {
        dst_l = stg[st + base + lane] & 0xffff;
        float2 sd = ss[dst_l];
        float xh = sn.x - sd.x;
        xh = (xh >= 0.f) ? xh : 0.2f * xh;
        eh_l = __expf(-xh);
        float xl = sn.y + sd.y;
        xl = (xl >= 0.f) ? xl : 0.2f * xl;
        el_l = __expf(-xl);
      }
      int j = 0;
      for (; j + 8 <= m; j += 8) {
        uint32_t u[8]; float eh[8], el[8];
#pragma unroll
        for (int x = 0; x < 8; x++) {
          int dd = bcast_i(dst_l, j + x);
          u[x]  = HL[((uint32_t)dd << 6) + lane];
          eh[x] = bcast_f(eh_l, j + x);
          el[x] = bcast_f(el_l, j + x);
        }
#pragma unroll
        for (int x = 0; x < 8; x++) {
          accH += eh[x] * bfH(u[x]); accL += el[x] * bfL(u[x]);
          rsH += eh[x]; rsL += el[x];
        }
      }
      for (; j < m; j++) {
        int      dst = bcast_i(dst_l, j);
        float    eh  = bcast_f(eh_l, j);
        float    el  = bcast_f(el_l, j);
        uint32_t u   = HL[((uint32_t)dst << 6) + lane];
        accH += eh * bfH(u);
        accL += el * bfL(u);
        rsH += eh;
        rsL += el;
      }
    }

    float oh = accH / (rsH + 1e-16f);
    float ol = accL / (rsL + 1e-16f);
    out[(size_t)node * 128 + lane]      = leaky01(oh);
    out[(size_t)node * 128 + 64 + lane] = leaky01(ol);
  }
}

// -------------------------------------------------------------------------
extern "C" void kernel_launch(void* const* d_in, const int* in_sizes, int n_in,
                              void* d_out, int out_size, void* d_ws, size_t ws_size,
                              hipStream_t stream) {
  const float* inp  = (const float*)d_in[0];
  const int*   edge = (const int*)d_in[1];
  const float* Wh   = (const float*)d_in[2];
  const float* Wl   = (const float*)d_in[3];
  const float* ah   = (const float*)d_in[4];
  const float* al   = (const float*)d_in[5];
  float* out = (float*)d_out;

  char* ws = (char*)d_ws;
  uint32_t* HL     = (uint32_t*)(ws + 0);          // 12,800,000 B
  float2*   ss     = (float2*)  (ws + 12800000);   //    400,000 B
  uint32_t* binned = (uint32_t*)(ws + 13200000);   //  8,028,160 B
  int*      cursor = (int*)     (ws + 21228160);   //      1,024 B
  __hip_bfloat16* Wt = (__hip_bfloat16*)(ws + 21229184);  // 65,536 B

  prep_kernel<<<128, 256, 0, stream>>>(Wh, Wl, Wt, cursor);
  fused_kernel<<<NBIN + NGEMM, 256, 0, stream>>>(inp, Wt, ah, al, edge,
                                                 cursor, binned, HL, ss);
  agg_kernel<<<BKT * 8, 256, 0, stream>>>(binned, cursor, HL, ss, out);
}